// Round 6
// baseline (668.351 us; speedup 1.0000x reference)
//
#include <hip/hip_runtime.h>

typedef __attribute__((ext_vector_type(4))) float f32x4;
typedef __attribute__((ext_vector_type(8))) short bf16x8;

__device__ inline ushort f2bf(float f) {
    uint u = __builtin_bit_cast(uint, f);
    u += 0x7fff + ((u >> 16) & 1);          // round-to-nearest-even
    return (ushort)(u >> 16);
}
__device__ inline float bf2f(ushort h) {
    uint u = ((uint)h) << 16;
    return __builtin_bit_cast(float, u);
}

#define GRP 8          // XCD count
#define NSLICE 6250    // 50000 / 8 (nodes per source slice)
#define CHUNK 2048     // edges per block-chunk in hist/fill

// ---------------- XCD-partitioned histogram over 400K buckets (dst*8 + src_slice) ----------------
__global__ __launch_bounds__(256) void k_hist_p(const int* __restrict__ ei,
                                                int* __restrict__ cnt8, int nE) {
    const int g = blockIdx.x & 7;
    const int c = blockIdx.x >> 3;
    const int lo = g * NSLICE, hi = lo + NSLICE;
    #pragma unroll
    for (int p = 0; p < CHUNK / 256; ++p) {
        int e = c * CHUNK + p * 256 + threadIdx.x;
        if (e < nE) {
            int d = ei[nE + e];
            int s = ei[e];
            if (d >= lo && d < hi) atomicAdd(&cnt8[d * 8 + s / NSLICE], 1);
        }
    }
}

// ---------------- block-local exclusive scan ----------------
__global__ __launch_bounds__(1024) void k_scan1(const int* __restrict__ cnt,
                                                int* __restrict__ rp,
                                                int* __restrict__ bsum, int n) {
    __shared__ int buf[1024];
    const int tid = threadIdx.x;
    const int i = blockIdx.x * 1024 + tid;
    int v = (i < n) ? cnt[i] : 0;
    buf[tid] = v;
    __syncthreads();
    #pragma unroll
    for (int off = 1; off < 1024; off <<= 1) {
        int t = 0;
        if (tid >= off) t = buf[tid - off];
        __syncthreads();
        if (tid >= off) buf[tid] += t;
        __syncthreads();
    }
    if (i < n) rp[i] = buf[tid] - v;
    if (tid == 1023) bsum[blockIdx.x] = buf[1023];
}

// ---------------- wave-parallel scan of block sums ----------------
__global__ void k_scan2(const int* __restrict__ bsum, int* __restrict__ bofs,
                        int* __restrict__ rp, int nb, int n) {
    const int lane = threadIdx.x & 63;
    int carry = 0;
    for (int c = 0; c * 64 < nb; ++c) {
        int i = c * 64 + lane;
        int v = (i < nb) ? bsum[i] : 0;
        int s = v;
        #pragma unroll
        for (int off = 1; off < 64; off <<= 1) {
            int t = __shfl_up(s, off, 64);
            if (lane >= off) s += t;
        }
        if (i < nb) bofs[i] = carry + s - v;
        carry += __shfl(s, 63, 64);
    }
    if (lane == 0) rp[n] = carry;
}

__global__ __launch_bounds__(1024) void k_scan3(int* __restrict__ rp,
                                                const int* __restrict__ bofs, int n) {
    int i = blockIdx.x * 1024 + threadIdx.x;
    if (i < n) rp[i] += bofs[blockIdx.x];
}

// ---------------- XCD-partitioned counting-sort fill over 400K buckets ----------------
__global__ __launch_bounds__(256) void k_fill_p(const int* __restrict__ ei,
                                                const int* __restrict__ rp8,
                                                int* __restrict__ cur8,
                                                int* __restrict__ srt, int nE) {
    const int g = blockIdx.x & 7;
    const int c = blockIdx.x >> 3;
    const int lo = g * NSLICE, hi = lo + NSLICE;
    #pragma unroll
    for (int p = 0; p < CHUNK / 256; ++p) {
        int e = c * CHUNK + p * 256 + threadIdx.x;
        if (e < nE) {
            int d = ei[nE + e];
            int s = ei[e];
            if (d >= lo && d < hi) {
                int k = d * 8 + s / NSLICE;
                int pos = rp8[k] + atomicAdd(&cur8[k], 1);
                srt[pos] = s;
            }
        }
    }
}

// ---------------- fused convert: x -> A1[:,128:256) bf16, weights -> W1cat/W2cat ----------------
__global__ __launch_bounds__(256) void k_cvt(const float* __restrict__ x,
                                             const float* __restrict__ Wl1,
                                             const float* __restrict__ Wr1,
                                             const float* __restrict__ Wl2,
                                             const float* __restrict__ Wr2,
                                             ushort* __restrict__ A1,
                                             ushort* __restrict__ W1cat,
                                             ushort* __restrict__ W2cat, int n) {
    const int nxb = (n * 32 + 255) / 256;
    if (blockIdx.x < nxb) {
        int e4 = blockIdx.x * 256 + threadIdx.x;
        if (e4 >= n * 32) return;
        int i = e4 >> 5, c4 = e4 & 31;
        float4 v = *(const float4*)(x + (size_t)i * 128 + c4 * 4);
        ushort4 o;
        o.x = f2bf(v.x); o.y = f2bf(v.y); o.z = f2bf(v.z); o.w = f2bf(v.w);
        *(ushort4*)(A1 + (size_t)i * 256 + 128 + c4 * 4) = o;
        return;
    }
    int t = (blockIdx.x - nxb) * 256 + threadIdx.x;   // 0..32767
    int which = t >> 14;
    int r = (t >> 6) & 255;
    int kq = t & 63;
    const float* src;
    ushort* dst;
    if (which == 0) {
        src = (kq < 32) ? (Wl1 + (size_t)r * 128 + kq * 4)
                        : (Wr1 + (size_t)r * 128 + (kq - 32) * 4);
        dst = W1cat + (size_t)r * 256 + kq * 4;
    } else {
        src = (r < 128) ? (Wl2 + (size_t)r * 256 + kq * 4)
                        : (Wr2 + (size_t)(r - 128) * 256 + kq * 4);
        dst = W2cat + (size_t)r * 256 + kq * 4;
    }
    float4 v = *(const float4*)src;
    ushort4 o;
    o.x = f2bf(v.x); o.y = f2bf(v.y); o.z = f2bf(v.z); o.w = f2bf(v.w);
    *(ushort4*)dst = o;
}

// ---------------- slice-phased gather, 8 nodes per wave ----------------
// gather1: A1[i][0:128) = mean_{s in N(i)} A1[s][128:256)
__global__ __launch_bounds__(256) void k_gather1(ushort* A1,
                                                 const int* __restrict__ srt,
                                                 const int* __restrict__ rp8, int n) {
    const int wav = blockIdx.x * 4 + (threadIdx.x >> 6);
    const int base = wav * 8;
    if (base >= n) return;
    const int lane = threadIdx.x & 63;
    float ax[8] = {}, ay[8] = {};
    int deg[8] = {};
    int curq[8], endq[8];
    #pragma unroll
    for (int q = 0; q < 8; ++q)
        curq[q] = (base + q < n) ? rp8[(base + q) * 8] : 0;

    #pragma unroll
    for (int p = 0; p < 8; ++p) {
        #pragma unroll
        for (int q = 0; q < 8; ++q) {
            endq[q] = (base + q < n) ? rp8[(base + q) * 8 + p + 1] : 0;
            deg[q] += endq[q] - curq[q];
        }
        bool any = true;
        while (any) {
            any = false;
            uint v[8]; bool live[8];
            #pragma unroll
            for (int q = 0; q < 8; ++q) {
                live[q] = curq[q] < endq[q];
                if (live[q]) {
                    int s = srt[curq[q]++];
                    v[q] = *(const uint*)(A1 + (size_t)s * 256 + 128 + lane * 2);
                    any = true;
                }
            }
            #pragma unroll
            for (int q = 0; q < 8; ++q)
                if (live[q]) {
                    ax[q] += bf2f((ushort)v[q]);
                    ay[q] += bf2f((ushort)(v[q] >> 16));
                }
        }
    }
    #pragma unroll
    for (int q = 0; q < 8; ++q) {
        const int node = base + q;
        if (node < n) {
            const float invd = 1.0f / fmaxf((float)deg[q], 1.0f);
            uint o = ((uint)f2bf(ay[q] * invd) << 16) | (uint)f2bf(ax[q] * invd);
            *(uint*)(A1 + (size_t)node * 256 + lane * 2) = o;
        }
    }
}

// gather2 + finalize: out[i] = mean_{s in N(i)} t2[s] + rbuf[i] + b2
// H2 layout: [i][0:128)=t2 (bf16), [i][128:256)=rbuf (bf16)
__global__ __launch_bounds__(256) void k_gather2(const ushort* __restrict__ H2,
                                                 const int* __restrict__ srt,
                                                 const int* __restrict__ rp8,
                                                 const float* __restrict__ b2,
                                                 float* __restrict__ out, int n) {
    const int wav = blockIdx.x * 4 + (threadIdx.x >> 6);
    const int base = wav * 8;
    if (base >= n) return;
    const int lane = threadIdx.x & 63;
    float ax[8] = {}, ay[8] = {};
    int deg[8] = {};
    int curq[8], endq[8];
    #pragma unroll
    for (int q = 0; q < 8; ++q)
        curq[q] = (base + q < n) ? rp8[(base + q) * 8] : 0;

    #pragma unroll
    for (int p = 0; p < 8; ++p) {
        #pragma unroll
        for (int q = 0; q < 8; ++q) {
            endq[q] = (base + q < n) ? rp8[(base + q) * 8 + p + 1] : 0;
            deg[q] += endq[q] - curq[q];
        }
        bool any = true;
        while (any) {
            any = false;
            uint v[8]; bool live[8];
            #pragma unroll
            for (int q = 0; q < 8; ++q) {
                live[q] = curq[q] < endq[q];
                if (live[q]) {
                    int s = srt[curq[q]++];
                    v[q] = *(const uint*)(H2 + (size_t)s * 256 + lane * 2);
                    any = true;
                }
            }
            #pragma unroll
            for (int q = 0; q < 8; ++q)
                if (live[q]) {
                    ax[q] += bf2f((ushort)v[q]);
                    ay[q] += bf2f((ushort)(v[q] >> 16));
                }
        }
    }
    float2 bb = *(const float2*)(b2 + lane * 2);
    #pragma unroll
    for (int q = 0; q < 8; ++q) {
        const int node = base + q;
        if (node < n) {
            const float invd = 1.0f / fmaxf((float)deg[q], 1.0f);
            uint rv = *(const uint*)(H2 + (size_t)node * 256 + 128 + lane * 2);
            float2 res;
            res.x = ax[q] * invd + bf2f((ushort)rv) + bb.x;
            res.y = ay[q] * invd + bf2f((ushort)(rv >> 16)) + bb.y;
            *(float2*)(out + (size_t)node * 128 + lane * 2) = res;
        }
    }
}

// ---------------- fused 2-layer MFMA GEMM (unchanged from R5) ----------------
__global__ __launch_bounds__(512, 4) void k_gemm_fused(
    const ushort* __restrict__ A, const ushort* __restrict__ W1,
    const ushort* __restrict__ W2, const float* __restrict__ b1,
    ushort* __restrict__ O, int n)
{
    __shared__ __align__(16) char sA[32768];   // 64 rows x 512 B, swizzled
    __shared__ __align__(16) char sH[32768];
    const int bi = blockIdx.x * 64;
    const int tid = threadIdx.x;

    #pragma unroll
    for (int p = 0; p < 4; ++p) {
        const int o = p * 8192 + tid * 16;
        const int row = o >> 9;
        const int cb = o & 511;
        uint4 v = *(const uint4*)((const char*)A + (size_t)(bi + row) * 512 + cb);
        *(uint4*)(sA + row * 512 + (cb ^ ((row & 7) << 4))) = v;
    }
    __syncthreads();

    const int wid = tid >> 6;
    const int lane = tid & 63;
    const int wn = wid * 32;
    const int lr = lane & 15;
    const int lkb = (lane >> 4) * 16;
    const int crow0 = (lane >> 4) * 4;
    const int ccol = lane & 15;

    // ---- GEMM 1: H = A @ W1^T + b1 ----
    {
        f32x4 acc[4][2] = {};
        #pragma unroll
        for (int kk = 0; kk < 8; ++kk) {
            bf16x8 wf[2], af[4];
            #pragma unroll
            for (int ni = 0; ni < 2; ++ni)
                wf[ni] = *(const bf16x8*)((const char*)W1 + (size_t)(wn + ni * 16 + lr) * 512 + kk * 64 + lkb);
            #pragma unroll
            for (int mi = 0; mi < 4; ++mi) {
                const int row = mi * 16 + lr;
                af[mi] = *(const bf16x8*)(sA + row * 512 + ((kk * 64 + lkb) ^ ((row & 7) << 4)));
            }
            #pragma unroll
            for (int mi = 0; mi < 4; ++mi)
                #pragma unroll
                for (int ni = 0; ni < 2; ++ni)
                    acc[mi][ni] = __builtin_amdgcn_mfma_f32_16x16x32_bf16(
                        af[mi], wf[ni], acc[mi][ni], 0, 0, 0);
        }
        const float badd0 = b1[wn + ccol];
        const float badd1 = b1[wn + 16 + ccol];
        #pragma unroll
        for (int mi = 0; mi < 4; ++mi)
            #pragma unroll
            for (int ni = 0; ni < 2; ++ni) {
                const int col = wn + ni * 16 + ccol;
                const float badd = ni ? badd1 : badd0;
                #pragma unroll
                for (int j = 0; j < 4; ++j) {
                    const int row = mi * 16 + crow0 + j;
                    *(ushort*)(sH + row * 512 + ((col * 2) ^ ((row & 7) << 4))) =
                        f2bf(acc[mi][ni][j] + badd);
                }
            }
    }
    __syncthreads();

    // ---- GEMM 2: O = H @ W2^T ----
    {
        f32x4 acc[4][2] = {};
        #pragma unroll
        for (int kk = 0; kk < 8; ++kk) {
            bf16x8 wf[2], af[4];
            #pragma unroll
            for (int ni = 0; ni < 2; ++ni)
                wf[ni] = *(const bf16x8*)((const char*)W2 + (size_t)(wn + ni * 16 + lr) * 512 + kk * 64 + lkb);
            #pragma unroll
            for (int mi = 0; mi < 4; ++mi) {
                const int row = mi * 16 + lr;
                af[mi] = *(const bf16x8*)(sH + row * 512 + ((kk * 64 + lkb) ^ ((row & 7) << 4)));
            }
            #pragma unroll
            for (int mi = 0; mi < 4; ++mi)
                #pragma unroll
                for (int ni = 0; ni < 2; ++ni)
                    acc[mi][ni] = __builtin_amdgcn_mfma_f32_16x16x32_bf16(
                        af[mi], wf[ni], acc[mi][ni], 0, 0, 0);
        }
        #pragma unroll
        for (int mi = 0; mi < 4; ++mi)
            #pragma unroll
            for (int ni = 0; ni < 2; ++ni) {
                const int ocol = wn + ni * 16 + ccol;
                #pragma unroll
                for (int j = 0; j < 4; ++j) {
                    const int grow = bi + mi * 16 + crow0 + j;
                    if (grow < n)
                        O[(size_t)grow * 256 + ocol] = f2bf(acc[mi][ni][j]);
                }
            }
    }
}

extern "C" void kernel_launch(void* const* d_in, const int* in_sizes, int n_in,
                              void* d_out, int out_size, void* d_ws, size_t ws_size,
                              hipStream_t stream) {
    const float* x   = (const float*)d_in[0];
    const int*   ei  = (const int*)  d_in[1];
    const float* Wl1 = (const float*)d_in[2];
    const float* bl1 = (const float*)d_in[3];
    const float* Wr1 = (const float*)d_in[4];
    const float* Wl2 = (const float*)d_in[5];
    const float* bl2 = (const float*)d_in[6];
    const float* Wr2 = (const float*)d_in[7];
    float* out = (float*)d_out;

    const int nN = 50000;
    const int nE = in_sizes[1] / 2;   // 800000
    const int n8 = nN * 8;            // 400000 buckets

    char* ws = (char*)d_ws;
    int*    rp8   = (int*)   (ws);                                    // 400001 ints
    int*    cnt8  = (int*)   (ws + (size_t)2 * (1 << 20));            // 1.6 MB
    int*    cur8  = (int*)   (ws + (size_t)2 * (1 << 20) + 1600000);  // 1.6 MB
    int*    bsum  = (int*)   (ws + (size_t)6 * (1 << 20));
    int*    bofs  = (int*)   (ws + (size_t)6 * (1 << 20) + 4096);
    int*    srt   = (int*)   (ws + (size_t)7 * (1 << 20));            // 3.2 MB
    ushort* W1cat = (ushort*)(ws + (size_t)11 * (1 << 20));           // 128 KB
    ushort* W2cat = (ushort*)(ws + (size_t)11 * (1 << 20) + 262144);
    ushort* A1    = (ushort*)(ws + (size_t)12 * (1 << 20));           // 25.6 MB (+pad rows)
    ushort* H2    = (ushort*)(ws + (size_t)38 * (1 << 20));           // 25.6 MB (+pad rows)

    const int nb8 = (n8 + 1023) / 1024;            // 391
    const int nChunks = (nE + CHUNK - 1) / CHUNK;  // 391
    const int nxb = (nN * 32 + 255) / 256;         // cvt blocks for x

    // ---- build slice-bucketed CSR ----
    hipMemsetAsync(cnt8, 0, (size_t)2 * 1600000, stream);   // cnt8 + cur8
    k_hist_p<<<nChunks * GRP, 256, 0, stream>>>(ei, cnt8, nE);
    k_scan1<<<nb8, 1024, 0, stream>>>(cnt8, rp8, bsum, n8);
    k_scan2<<<1, 64, 0, stream>>>(bsum, bofs, rp8, nb8, n8);
    k_scan3<<<nb8, 1024, 0, stream>>>(rp8, bofs, n8);
    k_fill_p<<<nChunks * GRP, 256, 0, stream>>>(ei, rp8, cur8, srt, nE);

    // ---- bf16 conversions (x + weights, one launch) ----
    k_cvt<<<nxb + 128, 256, 0, stream>>>(x, Wl1, Wr1, Wl2, Wr2, A1, W1cat, W2cat, nN);

    // ---- layer 1 aggregation (slice-phased), then fused dual-layer GEMM ----
    k_gather1<<<(nN + 31) / 32, 256, 0, stream>>>(A1, srt, rp8, nN);
    k_gemm_fused<<<(nN + 63) / 64, 512, 0, stream>>>(A1, W1cat, W2cat, bl1, H2, nN);

    // ---- layer 2 aggregation + finalize (slice-phased) ----
    k_gather2<<<(nN + 31) / 32, 256, 0, stream>>>(H2, srt, rp8, bl2, out, nN);
}

// Round 7
// 288.622 us; speedup vs baseline: 2.3157x; 2.3157x over previous
//
#include <hip/hip_runtime.h>

typedef __attribute__((ext_vector_type(4))) float f32x4;
typedef __attribute__((ext_vector_type(8))) short bf16x8;

__device__ inline ushort f2bf(float f) {
    uint u = __builtin_bit_cast(uint, f);
    u += 0x7fff + ((u >> 16) & 1);          // round-to-nearest-even
    return (ushort)(u >> 16);
}
__device__ inline float bf2f(ushort h) {
    uint u = ((uint)h) << 16;
    return __builtin_bit_cast(float, u);
}

#define GRP 8          // XCD count; blockIdx.x & 7 ~ XCD id under round-robin dispatch
#define NSLICE 6250    // 50000 / 8 (dst nodes per partition)
#define CHUNK 2048     // edges per block-chunk in hist/fill

// ---------------- XCD-partitioned histogram of dst (50K buckets) ----------------
__global__ __launch_bounds__(256) void k_hist_p(const int* __restrict__ ei,
                                                int* __restrict__ cnt, int nE) {
    const int g = blockIdx.x & 7;
    const int c = blockIdx.x >> 3;
    const int lo = g * NSLICE, hi = lo + NSLICE;
    #pragma unroll
    for (int p = 0; p < CHUNK / 256; ++p) {
        int e = c * CHUNK + p * 256 + threadIdx.x;
        if (e < nE) {
            int d = ei[nE + e];
            if (d >= lo && d < hi) atomicAdd(&cnt[d], 1);
        }
    }
}

// ---------------- block-local exclusive scan ----------------
__global__ __launch_bounds__(1024) void k_scan1(const int* __restrict__ cnt,
                                                int* __restrict__ rp,
                                                int* __restrict__ bsum, int n) {
    __shared__ int buf[1024];
    const int tid = threadIdx.x;
    const int i = blockIdx.x * 1024 + tid;
    int v = (i < n) ? cnt[i] : 0;
    buf[tid] = v;
    __syncthreads();
    #pragma unroll
    for (int off = 1; off < 1024; off <<= 1) {
        int t = 0;
        if (tid >= off) t = buf[tid - off];
        __syncthreads();
        if (tid >= off) buf[tid] += t;
        __syncthreads();
    }
    if (i < n) rp[i] = buf[tid] - v;
    if (tid == 1023) bsum[blockIdx.x] = buf[1023];
}

// ---------------- wave-parallel scan of block sums ----------------
__global__ void k_scan2(const int* __restrict__ bsum, int* __restrict__ bofs,
                        int* __restrict__ rp, int nb, int n) {
    const int lane = threadIdx.x & 63;
    int carry = 0;
    for (int c = 0; c * 64 < nb; ++c) {
        int i = c * 64 + lane;
        int v = (i < nb) ? bsum[i] : 0;
        int s = v;
        #pragma unroll
        for (int off = 1; off < 64; off <<= 1) {
            int t = __shfl_up(s, off, 64);
            if (lane >= off) s += t;
        }
        if (i < nb) bofs[i] = carry + s - v;
        carry += __shfl(s, 63, 64);
    }
    if (lane == 0) rp[n] = carry;
}

__global__ __launch_bounds__(1024) void k_scan3(int* __restrict__ rp,
                                                const int* __restrict__ bofs, int n) {
    int i = blockIdx.x * 1024 + threadIdx.x;
    if (i < n) rp[i] += bofs[blockIdx.x];
}

// ---------------- XCD-partitioned counting-sort fill ----------------
__global__ __launch_bounds__(256) void k_fill_p(const int* __restrict__ ei,
                                                const int* __restrict__ rp,
                                                int* __restrict__ cur,
                                                int* __restrict__ srt, int nE) {
    const int g = blockIdx.x & 7;
    const int c = blockIdx.x >> 3;
    const int lo = g * NSLICE, hi = lo + NSLICE;
    #pragma unroll
    for (int p = 0; p < CHUNK / 256; ++p) {
        int e = c * CHUNK + p * 256 + threadIdx.x;
        if (e < nE) {
            int d = ei[nE + e];
            int s = ei[e];
            if (d >= lo && d < hi) {
                int pos = rp[d] + atomicAdd(&cur[d], 1);
                srt[pos] = s;
            }
        }
    }
}

// ---------------- fused convert: x -> A1[:,128:256) bf16, weights -> W1cat/W2cat ----------------
__global__ __launch_bounds__(256) void k_cvt(const float* __restrict__ x,
                                             const float* __restrict__ Wl1,
                                             const float* __restrict__ Wr1,
                                             const float* __restrict__ Wl2,
                                             const float* __restrict__ Wr2,
                                             ushort* __restrict__ A1,
                                             ushort* __restrict__ W1cat,
                                             ushort* __restrict__ W2cat, int n) {
    const int nxb = (n * 32 + 255) / 256;
    if (blockIdx.x < nxb) {
        int e4 = blockIdx.x * 256 + threadIdx.x;
        if (e4 >= n * 32) return;
        int i = e4 >> 5, c4 = e4 & 31;
        float4 v = *(const float4*)(x + (size_t)i * 128 + c4 * 4);
        ushort4 o;
        o.x = f2bf(v.x); o.y = f2bf(v.y); o.z = f2bf(v.z); o.w = f2bf(v.w);
        *(ushort4*)(A1 + (size_t)i * 256 + 128 + c4 * 4) = o;
        return;
    }
    int t = (blockIdx.x - nxb) * 256 + threadIdx.x;   // 0..32767
    int which = t >> 14;
    int r = (t >> 6) & 255;
    int kq = t & 63;
    const float* src;
    ushort* dst;
    if (which == 0) {
        src = (kq < 32) ? (Wl1 + (size_t)r * 128 + kq * 4)
                        : (Wr1 + (size_t)r * 128 + (kq - 32) * 4);
        dst = W1cat + (size_t)r * 256 + kq * 4;
    } else {
        src = (r < 128) ? (Wl2 + (size_t)r * 256 + kq * 4)
                        : (Wr2 + (size_t)(r - 128) * 256 + kq * 4);
        dst = W2cat + (size_t)r * 256 + kq * 4;
    }
    float4 v = *(const float4*)src;
    ushort4 o;
    o.x = f2bf(v.x); o.y = f2bf(v.y); o.z = f2bf(v.z); o.w = f2bf(v.w);
    *(ushort4*)dst = o;
}

// ---------------- gather1: A1[i][0:128) = mean_{s in N(i)} A1[s][128:256) ----------------
// One node per wave; 2 edges per load instruction (lanes 0-31 edge e, lanes 32-63 edge e+1;
// 8 B/lane), 8 loads (16 edges) in flight; shfl_xor(32) finish.
__global__ __launch_bounds__(256) void k_gather1(ushort* A1,
                                                 const int* __restrict__ srt,
                                                 const int* __restrict__ rp, int n) {
    const int node = blockIdx.x * 4 + (threadIdx.x >> 6);
    if (node >= n) return;
    const int lane = threadIdx.x & 63;
    const int half = lane >> 5;
    const int col8 = (lane & 31) * 8;      // byte offset within 256B half-row
    const int beg = rp[node], end = rp[node + 1];
    float a0 = 0.f, a1 = 0.f, a2 = 0.f, a3 = 0.f;
    int e = beg;
    for (; e + 15 < end; e += 16) {
        uint2 v[8];
        #pragma unroll
        for (int q = 0; q < 8; ++q) {
            int s = srt[e + q * 2 + half];
            v[q] = *(const uint2*)((const char*)A1 + (size_t)s * 512 + 256 + col8);
        }
        #pragma unroll
        for (int q = 0; q < 8; ++q) {
            a0 += bf2f((ushort)v[q].x);  a1 += bf2f((ushort)(v[q].x >> 16));
            a2 += bf2f((ushort)v[q].y);  a3 += bf2f((ushort)(v[q].y >> 16));
        }
    }
    for (; e + 1 < end; e += 2) {
        int s = srt[e + half];
        uint2 v = *(const uint2*)((const char*)A1 + (size_t)s * 512 + 256 + col8);
        a0 += bf2f((ushort)v.x);  a1 += bf2f((ushort)(v.x >> 16));
        a2 += bf2f((ushort)v.y);  a3 += bf2f((ushort)(v.y >> 16));
    }
    if (e < end && half == 0) {
        int s = srt[e];
        uint2 v = *(const uint2*)((const char*)A1 + (size_t)s * 512 + 256 + col8);
        a0 += bf2f((ushort)v.x);  a1 += bf2f((ushort)(v.x >> 16));
        a2 += bf2f((ushort)v.y);  a3 += bf2f((ushort)(v.y >> 16));
    }
    a0 += __shfl_xor(a0, 32); a1 += __shfl_xor(a1, 32);
    a2 += __shfl_xor(a2, 32); a3 += __shfl_xor(a3, 32);
    if (half == 0) {
        const float invd = 1.0f / fmaxf((float)(end - beg), 1.0f);
        ushort4 o;
        o.x = f2bf(a0 * invd); o.y = f2bf(a1 * invd);
        o.z = f2bf(a2 * invd); o.w = f2bf(a3 * invd);
        *(ushort4*)((char*)A1 + (size_t)node * 512 + col8) = o;
    }
}

// ---------------- gather2 + finalize: out[i] = mean(t2[nbrs]) + rbuf[i] + b2 ----------------
// H2 layout: [i][0:128)=t2 (bf16), [i][128:256)=rbuf (bf16)
__global__ __launch_bounds__(256) void k_gather2(const ushort* __restrict__ H2,
                                                 const int* __restrict__ srt,
                                                 const int* __restrict__ rp,
                                                 const float* __restrict__ b2,
                                                 float* __restrict__ out, int n) {
    const int node = blockIdx.x * 4 + (threadIdx.x >> 6);
    if (node >= n) return;
    const int lane = threadIdx.x & 63;
    const int half = lane >> 5;
    const int col8 = (lane & 31) * 8;
    const int beg = rp[node], end = rp[node + 1];
    float a0 = 0.f, a1 = 0.f, a2 = 0.f, a3 = 0.f;
    int e = beg;
    for (; e + 15 < end; e += 16) {
        uint2 v[8];
        #pragma unroll
        for (int q = 0; q < 8; ++q) {
            int s = srt[e + q * 2 + half];
            v[q] = *(const uint2*)((const char*)H2 + (size_t)s * 512 + col8);
        }
        #pragma unroll
        for (int q = 0; q < 8; ++q) {
            a0 += bf2f((ushort)v[q].x);  a1 += bf2f((ushort)(v[q].x >> 16));
            a2 += bf2f((ushort)v[q].y);  a3 += bf2f((ushort)(v[q].y >> 16));
        }
    }
    for (; e + 1 < end; e += 2) {
        int s = srt[e + half];
        uint2 v = *(const uint2*)((const char*)H2 + (size_t)s * 512 + col8);
        a0 += bf2f((ushort)v.x);  a1 += bf2f((ushort)(v.x >> 16));
        a2 += bf2f((ushort)v.y);  a3 += bf2f((ushort)(v.y >> 16));
    }
    if (e < end && half == 0) {
        int s = srt[e];
        uint2 v = *(const uint2*)((const char*)H2 + (size_t)s * 512 + col8);
        a0 += bf2f((ushort)v.x);  a1 += bf2f((ushort)(v.x >> 16));
        a2 += bf2f((ushort)v.y);  a3 += bf2f((ushort)(v.y >> 16));
    }
    a0 += __shfl_xor(a0, 32); a1 += __shfl_xor(a1, 32);
    a2 += __shfl_xor(a2, 32); a3 += __shfl_xor(a3, 32);
    if (half == 0) {
        const float invd = 1.0f / fmaxf((float)(end - beg), 1.0f);
        uint2 rv = *(const uint2*)((const char*)H2 + (size_t)node * 512 + 256 + col8);
        float4 bb = *(const float4*)(b2 + (lane & 31) * 4);
        float4 res;
        res.x = a0 * invd + bf2f((ushort)rv.x) + bb.x;
        res.y = a1 * invd + bf2f((ushort)(rv.x >> 16)) + bb.y;
        res.z = a2 * invd + bf2f((ushort)rv.y) + bb.z;
        res.w = a3 * invd + bf2f((ushort)(rv.y >> 16)) + bb.w;
        *(float4*)(out + (size_t)node * 128 + (lane & 31) * 4) = res;
    }
}

// ---------------- fused 2-layer MFMA GEMM ----------------
// Per 64-row block:  Htile = A1tile @ W1^T + b1  (into LDS, bf16, swizzled)
//                    O     = Htile  @ W2^T       (to global)
__global__ __launch_bounds__(512, 4) void k_gemm_fused(
    const ushort* __restrict__ A, const ushort* __restrict__ W1,
    const ushort* __restrict__ W2, const float* __restrict__ b1,
    ushort* __restrict__ O, int n)
{
    __shared__ __align__(16) char sA[32768];   // 64 rows x 512 B, swizzled
    __shared__ __align__(16) char sH[32768];
    const int bi = blockIdx.x * 64;
    const int tid = threadIdx.x;

    #pragma unroll
    for (int p = 0; p < 4; ++p) {
        const int o = p * 8192 + tid * 16;
        const int row = o >> 9;
        const int cb = o & 511;
        uint4 v = *(const uint4*)((const char*)A + (size_t)(bi + row) * 512 + cb);
        *(uint4*)(sA + row * 512 + (cb ^ ((row & 7) << 4))) = v;
    }
    __syncthreads();

    const int wid = tid >> 6;
    const int lane = tid & 63;
    const int wn = wid * 32;
    const int lr = lane & 15;
    const int lkb = (lane >> 4) * 16;
    const int crow0 = (lane >> 4) * 4;
    const int ccol = lane & 15;

    // ---- GEMM 1: H = A @ W1^T + b1 ----
    {
        f32x4 acc[4][2] = {};
        #pragma unroll
        for (int kk = 0; kk < 8; ++kk) {
            bf16x8 wf[2], af[4];
            #pragma unroll
            for (int ni = 0; ni < 2; ++ni)
                wf[ni] = *(const bf16x8*)((const char*)W1 + (size_t)(wn + ni * 16 + lr) * 512 + kk * 64 + lkb);
            #pragma unroll
            for (int mi = 0; mi < 4; ++mi) {
                const int row = mi * 16 + lr;
                af[mi] = *(const bf16x8*)(sA + row * 512 + ((kk * 64 + lkb) ^ ((row & 7) << 4)));
            }
            #pragma unroll
            for (int mi = 0; mi < 4; ++mi)
                #pragma unroll
                for (int ni = 0; ni < 2; ++ni)
                    acc[mi][ni] = __builtin_amdgcn_mfma_f32_16x16x32_bf16(
                        af[mi], wf[ni], acc[mi][ni], 0, 0, 0);
        }
        const float badd0 = b1[wn + ccol];
        const float badd1 = b1[wn + 16 + ccol];
        #pragma unroll
        for (int mi = 0; mi < 4; ++mi)
            #pragma unroll
            for (int ni = 0; ni < 2; ++ni) {
                const int col = wn + ni * 16 + ccol;
                const float badd = ni ? badd1 : badd0;
                #pragma unroll
                for (int j = 0; j < 4; ++j) {
                    const int row = mi * 16 + crow0 + j;
                    *(ushort*)(sH + row * 512 + ((col * 2) ^ ((row & 7) << 4))) =
                        f2bf(acc[mi][ni][j] + badd);
                }
            }
    }
    __syncthreads();

    // ---- GEMM 2: O = H @ W2^T ----
    {
        f32x4 acc[4][2] = {};
        #pragma unroll
        for (int kk = 0; kk < 8; ++kk) {
            bf16x8 wf[2], af[4];
            #pragma unroll
            for (int ni = 0; ni < 2; ++ni)
                wf[ni] = *(const bf16x8*)((const char*)W2 + (size_t)(wn + ni * 16 + lr) * 512 + kk * 64 + lkb);
            #pragma unroll
            for (int mi = 0; mi < 4; ++mi) {
                const int row = mi * 16 + lr;
                af[mi] = *(const bf16x8*)(sH + row * 512 + ((kk * 64 + lkb) ^ ((row & 7) << 4)));
            }
            #pragma unroll
            for (int mi = 0; mi < 4; ++mi)
                #pragma unroll
                for (int ni = 0; ni < 2; ++ni)
                    acc[mi][ni] = __builtin_amdgcn_mfma_f32_16x16x32_bf16(
                        af[mi], wf[ni], acc[mi][ni], 0, 0, 0);
        }
        #pragma unroll
        for (int mi = 0; mi < 4; ++mi)
            #pragma unroll
            for (int ni = 0; ni < 2; ++ni) {
                const int ocol = wn + ni * 16 + ccol;
                #pragma unroll
                for (int j = 0; j < 4; ++j) {
                    const int grow = bi + mi * 16 + crow0 + j;
                    if (grow < n)
                        O[(size_t)grow * 256 + ocol] = f2bf(acc[mi][ni][j]);
                }
            }
    }
}

extern "C" void kernel_launch(void* const* d_in, const int* in_sizes, int n_in,
                              void* d_out, int out_size, void* d_ws, size_t ws_size,
                              hipStream_t stream) {
    const float* x   = (const float*)d_in[0];
    const int*   ei  = (const int*)  d_in[1];
    const float* Wl1 = (const float*)d_in[2];
    const float* bl1 = (const float*)d_in[3];
    const float* Wr1 = (const float*)d_in[4];
    const float* Wl2 = (const float*)d_in[5];
    const float* bl2 = (const float*)d_in[6];
    const float* Wr2 = (const float*)d_in[7];
    float* out = (float*)d_out;

    const int nN = 50000;
    const int nE = in_sizes[1] / 2;   // 800000

    char* ws = (char*)d_ws;
    int*    rp    = (int*)   (ws);                              // (nN+1) ints
    int*    cnt   = (int*)   (ws + 262144);                     // nN ints
    int*    cur   = (int*)   (ws + 524288);                     // nN ints
    int*    bsum  = (int*)   (ws + 786432);
    int*    bofs  = (int*)   (ws + 790528);
    int*    srt   = (int*)   (ws + (size_t)1 * (1 << 20));      // 3.2 MB
    ushort* W1cat = (ushort*)(ws + (size_t)5 * (1 << 20));      // 128 KB
    ushort* W2cat = (ushort*)(ws + (size_t)5 * (1 << 20) + 262144);
    ushort* A1    = (ushort*)(ws + (size_t)6 * (1 << 20));      // 25.6 MB (+pad rows)
    ushort* H2    = (ushort*)(ws + (size_t)32 * (1 << 20));     // 25.6 MB (+pad rows)

    const int nb = (nN + 1023) / 1024;             // 49
    const int nChunks = (nE + CHUNK - 1) / CHUNK;  // 391
    const int nxb = (nN * 32 + 255) / 256;

    // ---- build CSR (dst-sorted src list), XCD-partitioned ----
    hipMemsetAsync(cnt, 0, 524288, stream);   // cnt + cur
    k_hist_p<<<nChunks * GRP, 256, 0, stream>>>(ei, cnt, nE);
    k_scan1<<<nb, 1024, 0, stream>>>(cnt, rp, bsum, nN);
    k_scan2<<<1, 64, 0, stream>>>(bsum, bofs, rp, nb, nN);
    k_scan3<<<nb, 1024, 0, stream>>>(rp, bofs, nN);
    k_fill_p<<<nChunks * GRP, 256, 0, stream>>>(ei, rp, cur, srt, nE);

    // ---- bf16 conversions (x + weights, one launch) ----
    k_cvt<<<nxb + 128, 256, 0, stream>>>(x, Wl1, Wr1, Wl2, Wr2, A1, W1cat, W2cat, nN);

    // ---- layer 1 aggregation, then fused dual-layer GEMM ----
    k_gather1<<<(nN + 3) / 4, 256, 0, stream>>>(A1, srt, rp, nN);
    k_gemm_fused<<<(nN + 63) / 64, 512, 0, stream>>>(A1, W1cat, W2cat, bl1, H2, nN);

    // ---- layer 2 aggregation + finalize ----
    k_gather2<<<(nN + 3) / 4, 256, 0, stream>>>(H2, srt, rp, bl2, out, nN);
}

// Round 8
// 269.679 us; speedup vs baseline: 2.4783x; 1.0702x over previous
//
#include <hip/hip_runtime.h>

typedef __attribute__((ext_vector_type(4))) float f32x4;
typedef __attribute__((ext_vector_type(8))) short bf16x8;

__device__ inline ushort f2bf(float f) {
    uint u = __builtin_bit_cast(uint, f);
    u += 0x7fff + ((u >> 16) & 1);          // round-to-nearest-even
    return (ushort)(u >> 16);
}
__device__ inline float bf2f(ushort h) {
    uint u = ((uint)h) << 16;
    return __builtin_bit_cast(float, u);
}
__device__ inline uint packbf(float lo, float hi) {
    return (uint)f2bf(lo) | ((uint)f2bf(hi) << 16);
}

#define GRP 8          // XCD count; blockIdx.x & 7 ~ XCD id under round-robin dispatch
#define NSLICE 6250    // 50000 / 8 (dst nodes per partition)
#define CHUNK 2048     // edges per block-chunk in hist/fill

// ---------------- fused pre-pass: x->bf16, weights->bf16, dst histogram ----------------
// blocks [0,nxb): x conversion; [nxb, nxb+128): weight conversion;
// [histBase, histBase + nChunks*8): XCD-partitioned histogram (histBase 8-aligned
// so (blockIdx - histBase) & 7 preserves the round-robin XCD identity).
__global__ __launch_bounds__(256) void k_pre(
    const float* __restrict__ x,
    const float* __restrict__ Wl1, const float* __restrict__ Wr1,
    const float* __restrict__ Wl2, const float* __restrict__ Wr2,
    const int* __restrict__ ei,
    ushort* __restrict__ A1, ushort* __restrict__ W1cat, ushort* __restrict__ W2cat,
    int* __restrict__ cnt, int n, int nE, int nxb, int histBase)
{
    const int b = blockIdx.x;
    if (b < nxb) {
        int e4 = b * 256 + threadIdx.x;
        if (e4 >= n * 32) return;
        int i = e4 >> 5, c4 = e4 & 31;
        float4 v = *(const float4*)(x + (size_t)i * 128 + c4 * 4);
        ushort4 o;
        o.x = f2bf(v.x); o.y = f2bf(v.y); o.z = f2bf(v.z); o.w = f2bf(v.w);
        *(ushort4*)(A1 + (size_t)i * 256 + 128 + c4 * 4) = o;
        return;
    }
    if (b < nxb + 128) {
        int t = (b - nxb) * 256 + threadIdx.x;   // 0..32767
        int which = t >> 14;
        int r = (t >> 6) & 255;
        int kq = t & 63;
        const float* src;
        ushort* dst;
        if (which == 0) {
            src = (kq < 32) ? (Wl1 + (size_t)r * 128 + kq * 4)
                            : (Wr1 + (size_t)r * 128 + (kq - 32) * 4);
            dst = W1cat + (size_t)r * 256 + kq * 4;
        } else {
            src = (r < 128) ? (Wl2 + (size_t)r * 256 + kq * 4)
                            : (Wr2 + (size_t)(r - 128) * 256 + kq * 4);
            dst = W2cat + (size_t)r * 256 + kq * 4;
        }
        float4 v = *(const float4*)src;
        ushort4 o;
        o.x = f2bf(v.x); o.y = f2bf(v.y); o.z = f2bf(v.z); o.w = f2bf(v.w);
        *(ushort4*)dst = o;
        return;
    }
    if (b < histBase) return;   // alignment padding blocks
    const int hb = b - histBase;
    const int g = hb & 7;
    const int c = hb >> 3;
    const int lo = g * NSLICE, hi = lo + NSLICE;
    #pragma unroll
    for (int p = 0; p < CHUNK / 256; ++p) {
        int e = c * CHUNK + p * 256 + threadIdx.x;
        if (e < nE) {
            int d = ei[nE + e];
            if (d >= lo && d < hi) atomicAdd(&cnt[d], 1);
        }
    }
}

// ---------------- block-local exclusive scan ----------------
__global__ __launch_bounds__(1024) void k_scan1(const int* __restrict__ cnt,
                                                int* __restrict__ rp,
                                                int* __restrict__ bsum, int n) {
    __shared__ int buf[1024];
    const int tid = threadIdx.x;
    const int i = blockIdx.x * 1024 + tid;
    int v = (i < n) ? cnt[i] : 0;
    buf[tid] = v;
    __syncthreads();
    #pragma unroll
    for (int off = 1; off < 1024; off <<= 1) {
        int t = 0;
        if (tid >= off) t = buf[tid - off];
        __syncthreads();
        if (tid >= off) buf[tid] += t;
        __syncthreads();
    }
    if (i < n) rp[i] = buf[tid] - v;
    if (tid == 1023) bsum[blockIdx.x] = buf[1023];
}

// ---------------- scan3 with inlined top-level scan (nb <= 64) ----------------
__global__ __launch_bounds__(1024) void k_scan3b(int* __restrict__ rp,
                                                 const int* __restrict__ bsum,
                                                 int nb, int n) {
    __shared__ int sofs;
    if (threadIdx.x < 64) {
        int i = threadIdx.x;
        int v = (i < nb) ? bsum[i] : 0;
        int s = v;
        #pragma unroll
        for (int off = 1; off < 64; off <<= 1) {
            int t = __shfl_up(s, off, 64);
            if (i >= off) s += t;
        }
        if (i == (int)blockIdx.x) sofs = s - v;
        if ((int)blockIdx.x == nb - 1 && i == nb - 1) rp[n] = s;
    }
    __syncthreads();
    int i = blockIdx.x * 1024 + threadIdx.x;
    if (i < n) rp[i] += sofs;
}

// ---------------- XCD-partitioned counting-sort fill ----------------
__global__ __launch_bounds__(256) void k_fill_p(const int* __restrict__ ei,
                                                const int* __restrict__ rp,
                                                int* __restrict__ cur,
                                                int* __restrict__ srt, int nE) {
    const int g = blockIdx.x & 7;
    const int c = blockIdx.x >> 3;
    const int lo = g * NSLICE, hi = lo + NSLICE;
    #pragma unroll
    for (int p = 0; p < CHUNK / 256; ++p) {
        int e = c * CHUNK + p * 256 + threadIdx.x;
        if (e < nE) {
            int d = ei[nE + e];
            if (d >= lo && d < hi) {
                int s = ei[e];
                int pos = rp[d] + atomicAdd(&cur[d], 1);
                srt[pos] = s;
            }
        }
    }
}

// ---------------- gather1: A1[i][0:128) = mean_{s in N(i)} A1[s][128:256) ----------------
// One node per wave; 4 edges per uint4 load (16B/lane x 16 lanes = one 256B row per
// quad-group), 4 loads (16 edges) per round regardless of degree (clamped dups are
// L2 hits). shfl_xor(16,32) reduce; lanes 0-15 write 16B.
__global__ __launch_bounds__(256) void k_gather1(ushort* A1,
                                                 const int* __restrict__ srt,
                                                 const int* __restrict__ rp, int n) {
    const int node = blockIdx.x * 4 + (threadIdx.x >> 6);
    if (node >= n) return;
    const int lane = threadIdx.x & 63;
    const int quad = lane >> 4;
    const int col16 = (lane & 15) * 16;    // byte offset within 256B half-row
    const int beg = rp[node], end = rp[node + 1];
    float a0 = 0.f, a1 = 0.f, a2 = 0.f, a3 = 0.f;
    float a4 = 0.f, a5 = 0.f, a6 = 0.f, a7 = 0.f;
    for (int e = beg; e < end; e += 16) {
        uint4 v[4]; int live[4];
        #pragma unroll
        for (int q = 0; q < 4; ++q) {
            int idx = e + q * 4 + quad;
            live[q] = idx < end;
            int s = srt[live[q] ? idx : end - 1];
            v[q] = *(const uint4*)((const char*)A1 + (size_t)s * 512 + 256 + col16);
        }
        #pragma unroll
        for (int q = 0; q < 4; ++q) {
            if (live[q]) {
                a0 += bf2f((ushort)v[q].x);  a1 += bf2f((ushort)(v[q].x >> 16));
                a2 += bf2f((ushort)v[q].y);  a3 += bf2f((ushort)(v[q].y >> 16));
                a4 += bf2f((ushort)v[q].z);  a5 += bf2f((ushort)(v[q].z >> 16));
                a6 += bf2f((ushort)v[q].w);  a7 += bf2f((ushort)(v[q].w >> 16));
            }
        }
    }
    a0 += __shfl_xor(a0, 16); a1 += __shfl_xor(a1, 16);
    a2 += __shfl_xor(a2, 16); a3 += __shfl_xor(a3, 16);
    a4 += __shfl_xor(a4, 16); a5 += __shfl_xor(a5, 16);
    a6 += __shfl_xor(a6, 16); a7 += __shfl_xor(a7, 16);
    a0 += __shfl_xor(a0, 32); a1 += __shfl_xor(a1, 32);
    a2 += __shfl_xor(a2, 32); a3 += __shfl_xor(a3, 32);
    a4 += __shfl_xor(a4, 32); a5 += __shfl_xor(a5, 32);
    a6 += __shfl_xor(a6, 32); a7 += __shfl_xor(a7, 32);
    if (quad == 0) {
        const float invd = 1.0f / fmaxf((float)(end - beg), 1.0f);
        uint4 o;
        o.x = packbf(a0 * invd, a1 * invd);
        o.y = packbf(a2 * invd, a3 * invd);
        o.z = packbf(a4 * invd, a5 * invd);
        o.w = packbf(a6 * invd, a7 * invd);
        *(uint4*)((char*)A1 + (size_t)node * 512 + col16) = o;
    }
}

// ---------------- gather2 + finalize: out[i] = mean(t2[nbrs]) + rbuf[i] + b2 ----------------
// H2 layout: [i][0:128)=t2 (bf16), [i][128:256)=rbuf (bf16)
__global__ __launch_bounds__(256) void k_gather2(const ushort* __restrict__ H2,
                                                 const int* __restrict__ srt,
                                                 const int* __restrict__ rp,
                                                 const float* __restrict__ b2,
                                                 float* __restrict__ out, int n) {
    const int node = blockIdx.x * 4 + (threadIdx.x >> 6);
    if (node >= n) return;
    const int lane = threadIdx.x & 63;
    const int quad = lane >> 4;
    const int col16 = (lane & 15) * 16;
    const int beg = rp[node], end = rp[node + 1];
    float a0 = 0.f, a1 = 0.f, a2 = 0.f, a3 = 0.f;
    float a4 = 0.f, a5 = 0.f, a6 = 0.f, a7 = 0.f;
    for (int e = beg; e < end; e += 16) {
        uint4 v[4]; int live[4];
        #pragma unroll
        for (int q = 0; q < 4; ++q) {
            int idx = e + q * 4 + quad;
            live[q] = idx < end;
            int s = srt[live[q] ? idx : end - 1];
            v[q] = *(const uint4*)((const char*)H2 + (size_t)s * 512 + col16);
        }
        #pragma unroll
        for (int q = 0; q < 4; ++q) {
            if (live[q]) {
                a0 += bf2f((ushort)v[q].x);  a1 += bf2f((ushort)(v[q].x >> 16));
                a2 += bf2f((ushort)v[q].y);  a3 += bf2f((ushort)(v[q].y >> 16));
                a4 += bf2f((ushort)v[q].z);  a5 += bf2f((ushort)(v[q].z >> 16));
                a6 += bf2f((ushort)v[q].w);  a7 += bf2f((ushort)(v[q].w >> 16));
            }
        }
    }
    a0 += __shfl_xor(a0, 16); a1 += __shfl_xor(a1, 16);
    a2 += __shfl_xor(a2, 16); a3 += __shfl_xor(a3, 16);
    a4 += __shfl_xor(a4, 16); a5 += __shfl_xor(a5, 16);
    a6 += __shfl_xor(a6, 16); a7 += __shfl_xor(a7, 16);
    a0 += __shfl_xor(a0, 32); a1 += __shfl_xor(a1, 32);
    a2 += __shfl_xor(a2, 32); a3 += __shfl_xor(a3, 32);
    a4 += __shfl_xor(a4, 32); a5 += __shfl_xor(a5, 32);
    a6 += __shfl_xor(a6, 32); a7 += __shfl_xor(a7, 32);
    if (quad == 0) {
        const float invd = 1.0f / fmaxf((float)(end - beg), 1.0f);
        uint4 rv = *(const uint4*)((const char*)H2 + (size_t)node * 512 + 256 + col16);
        const int c8 = (lane & 15) * 8;
        float4 bb0 = *(const float4*)(b2 + c8);
        float4 bb1 = *(const float4*)(b2 + c8 + 4);
        float4 r0, r1;
        r0.x = a0 * invd + bf2f((ushort)rv.x) + bb0.x;
        r0.y = a1 * invd + bf2f((ushort)(rv.x >> 16)) + bb0.y;
        r0.z = a2 * invd + bf2f((ushort)rv.y) + bb0.z;
        r0.w = a3 * invd + bf2f((ushort)(rv.y >> 16)) + bb0.w;
        r1.x = a4 * invd + bf2f((ushort)rv.z) + bb1.x;
        r1.y = a5 * invd + bf2f((ushort)(rv.z >> 16)) + bb1.y;
        r1.z = a6 * invd + bf2f((ushort)rv.w) + bb1.z;
        r1.w = a7 * invd + bf2f((ushort)(rv.w >> 16)) + bb1.w;
        *(float4*)(out + (size_t)node * 128 + c8) = r0;
        *(float4*)(out + (size_t)node * 128 + c8 + 4) = r1;
    }
}

// ---------------- fused 2-layer MFMA GEMM (single 32KB LDS buffer, reused for H) ----------------
// Per 64-row block:  Htile = A1tile @ W1^T + b1  -> overwrites sA (bf16, swizzled)
//                    O     = Htile  @ W2^T       -> global
// 512 threads = 8 waves, wave owns cols [wid*32, wid*32+32). W1/W2 from L2 (shared).
__global__ __launch_bounds__(512, 6) void k_gemm_fused(
    const ushort* __restrict__ A, const ushort* __restrict__ W1,
    const ushort* __restrict__ W2, const float* __restrict__ b1,
    ushort* __restrict__ O, int n)
{
    __shared__ __align__(16) char sA[32768];   // 64 rows x 512 B, swizzled; reused for H
    const int bi = blockIdx.x * 64;
    const int tid = threadIdx.x;

    #pragma unroll
    for (int p = 0; p < 4; ++p) {
        const int o = p * 8192 + tid * 16;
        const int row = o >> 9;
        const int cb = o & 511;
        uint4 v = *(const uint4*)((const char*)A + (size_t)(bi + row) * 512 + cb);
        *(uint4*)(sA + row * 512 + (cb ^ ((row & 7) << 4))) = v;
    }
    __syncthreads();

    const int wid = tid >> 6;
    const int lane = tid & 63;
    const int wn = wid * 32;
    const int lr = lane & 15;
    const int lkb = (lane >> 4) * 16;
    const int crow0 = (lane >> 4) * 4;
    const int ccol = lane & 15;

    // ---- GEMM 1: acc = A @ W1^T ----
    f32x4 acc[4][2] = {};
    #pragma unroll
    for (int kk = 0; kk < 8; ++kk) {
        bf16x8 wf[2], af[4];
        #pragma unroll
        for (int ni = 0; ni < 2; ++ni)
            wf[ni] = *(const bf16x8*)((const char*)W1 + (size_t)(wn + ni * 16 + lr) * 512 + kk * 64 + lkb);
        #pragma unroll
        for (int mi = 0; mi < 4; ++mi) {
            const int row = mi * 16 + lr;
            af[mi] = *(const bf16x8*)(sA + row * 512 + ((kk * 64 + lkb) ^ ((row & 7) << 4)));
        }
        #pragma unroll
        for (int mi = 0; mi < 4; ++mi)
            #pragma unroll
            for (int ni = 0; ni < 2; ++ni)
                acc[mi][ni] = __builtin_amdgcn_mfma_f32_16x16x32_bf16(
                    af[mi], wf[ni], acc[mi][ni], 0, 0, 0);
    }
    __syncthreads();   // all sA reads done; safe to overwrite with H

    {
        const float badd0 = b1[wn + ccol];
        const float badd1 = b1[wn + 16 + ccol];
        #pragma unroll
        for (int mi = 0; mi < 4; ++mi)
            #pragma unroll
            for (int ni = 0; ni < 2; ++ni) {
                const int col = wn + ni * 16 + ccol;
                const float badd = ni ? badd1 : badd0;
                #pragma unroll
                for (int j = 0; j < 4; ++j) {
                    const int row = mi * 16 + crow0 + j;
                    *(ushort*)(sA + row * 512 + ((col * 2) ^ ((row & 7) << 4))) =
                        f2bf(acc[mi][ni][j] + badd);
                }
            }
    }
    __syncthreads();

    // ---- GEMM 2: O = H @ W2^T ----
    {
        f32x4 acc2[4][2] = {};
        #pragma unroll
        for (int kk = 0; kk < 8; ++kk) {
            bf16x8 wf[2], af[4];
            #pragma unroll
            for (int ni = 0; ni < 2; ++ni)
                wf[ni] = *(const bf16x8*)((const char*)W2 + (size_t)(wn + ni * 16 + lr) * 512 + kk * 64 + lkb);
            #pragma unroll
            for (int mi = 0; mi < 4; ++mi) {
                const int row = mi * 16 + lr;
                af[mi] = *(const bf16x8*)(sA + row * 512 + ((kk * 64 + lkb) ^ ((row & 7) << 4)));
            }
            #pragma unroll
            for (int mi = 0; mi < 4; ++mi)
                #pragma unroll
                for (int ni = 0; ni < 2; ++ni)
                    acc2[mi][ni] = __builtin_amdgcn_mfma_f32_16x16x32_bf16(
                        af[mi], wf[ni], acc2[mi][ni], 0, 0, 0);
        }
        #pragma unroll
        for (int mi = 0; mi < 4; ++mi)
            #pragma unroll
            for (int ni = 0; ni < 2; ++ni) {
                const int ocol = wn + ni * 16 + ccol;
                #pragma unroll
                for (int j = 0; j < 4; ++j) {
                    const int grow = bi + mi * 16 + crow0 + j;
                    if (grow < n)
                        O[(size_t)grow * 256 + ocol] = f2bf(acc2[mi][ni][j]);
                }
            }
    }
}

extern "C" void kernel_launch(void* const* d_in, const int* in_sizes, int n_in,
                              void* d_out, int out_size, void* d_ws, size_t ws_size,
                              hipStream_t stream) {
    const float* x   = (const float*)d_in[0];
    const int*   ei  = (const int*)  d_in[1];
    const float* Wl1 = (const float*)d_in[2];
    const float* bl1 = (const float*)d_in[3];
    const float* Wr1 = (const float*)d_in[4];
    const float* Wl2 = (const float*)d_in[5];
    const float* bl2 = (const float*)d_in[6];
    const float* Wr2 = (const float*)d_in[7];
    float* out = (float*)d_out;

    const int nN = 50000;
    const int nE = in_sizes[1] / 2;   // 800000

    char* ws = (char*)d_ws;
    int*    rp    = (int*)   (ws);                              // (nN+1) ints
    int*    cnt   = (int*)   (ws + 262144);                     // nN ints
    int*    cur   = (int*)   (ws + 524288);                     // nN ints
    int*    bsum  = (int*)   (ws + 786432);
    int*    srt   = (int*)   (ws + (size_t)1 * (1 << 20));      // 3.2 MB
    ushort* W1cat = (ushort*)(ws + (size_t)5 * (1 << 20));      // 128 KB
    ushort* W2cat = (ushort*)(ws + (size_t)5 * (1 << 20) + 262144);
    ushort* A1    = (ushort*)(ws + (size_t)6 * (1 << 20));      // 25.6 MB (+pad rows)
    ushort* H2    = (ushort*)(ws + (size_t)32 * (1 << 20));     // 25.6 MB (+pad rows)

    const int nb = (nN + 1023) / 1024;             // 49
    const int nChunks = (nE + CHUNK - 1) / CHUNK;  // 391
    const int nxb = (nN * 32 + 255) / 256;         // 6250
    const int histBase = (nxb + 128 + 7) & ~7;     // 6384, 8-aligned

    hipMemsetAsync(cnt, 0, 524288, stream);        // cnt + cur

    // ---- pre-pass: conversions + histogram (one launch) ----
    k_pre<<<histBase + nChunks * GRP, 256, 0, stream>>>(
        x, Wl1, Wr1, Wl2, Wr2, ei, A1, W1cat, W2cat, cnt, nN, nE, nxb, histBase);

    // ---- CSR: scan + fill ----
    k_scan1<<<nb, 1024, 0, stream>>>(cnt, rp, bsum, nN);
    k_scan3b<<<nb, 1024, 0, stream>>>(rp, bsum, nb, nN);
    k_fill_p<<<nChunks * GRP, 256, 0, stream>>>(ei, rp, cur, srt, nE);

    // ---- layer 1 aggregation, fused dual-layer GEMM, layer 2 aggregation ----
    k_gather1<<<(nN + 3) / 4, 256, 0, stream>>>(A1, srt, rp, nN);
    k_gemm_fused<<<(nN + 63) / 64, 512, 0, stream>>>(A1, W1cat, W2cat, bl1, H2, nN);
    k_gather2<<<(nN + 3) / 4, 256, 0, stream>>>(H2, srt, rp, bl2, out, nN);
}